// Round 1
// baseline (4195.576 us; speedup 1.0000x reference)
//
#include <hip/hip_runtime.h>
#include <hip/hip_bf16.h>
#include <stdint.h>

typedef __attribute__((ext_vector_type(8))) short short8;
typedef __attribute__((ext_vector_type(4))) float f32x4;
typedef __attribute__((ext_vector_type(4))) float float4v;
typedef __attribute__((ext_vector_type(4))) int int4v;

#define MDIM 8192
#define NDIM 11008
#define KDIM 4096
#define BM 128
#define BN 128
#define BK 64
#define NBM (MDIM / BM)   /* 64 */
#define NBN (NDIM / BN)   /* 86 */

// round-to-nearest-even f32 -> bf16 (bit trick; NaN irrelevant for this data)
static __device__ __forceinline__ unsigned short f2bf(float f) {
  union { float f; unsigned int u; } v;
  v.f = f;
  unsigned int r = v.u + 0x7FFFu + ((v.u >> 16) & 1u);
  return (unsigned short)(r >> 16);
}

__global__ __launch_bounds__(256, 2) void clinear_mfma(
    const float* __restrict__ x,
    const int* __restrict__ qw,
    const float* __restrict__ scale,
    const float* __restrict__ bias,
    float* __restrict__ out)
{
  // bf16 tiles, 128 rows x 64 cols, XOR-swizzled 16B slots: 16 KB each
  __shared__ unsigned char ldsA[BM * BK * 2];
  __shared__ unsigned char ldsB[BN * BK * 2];

  const int t = threadIdx.x;
  const int lane = t & 63;
  const int wave = t >> 6;
  const int wr = wave >> 1;   // wave row (0..1) -> 64-row sub-tile
  const int wc = wave & 1;    // wave col (0..1) -> 64-col sub-tile

  // XCD-aware bijective block swizzle (nwg = 5504 = 8 * 688)
  const int bid = blockIdx.x;
  const int nwg = NBM * NBN;
  const int cpx = nwg >> 3;
  const int swz = (bid & 7) * cpx + (bid >> 3);
  const int bm = swz / NBN;
  const int bn = swz % NBN;

  // staging coords: 2 threads per tile row, 32 values each
  const int srow = t >> 1;          // 0..127
  const int shalf = t & 1;          // 0/1 -> col offset 0/32
  const float* aptr = x  + (size_t)(bm * BM + srow) * KDIM + shalf * 32;
  const int*   bptr = qw + (size_t)(bn * BN + srow) * KDIM + shalf * 32;
  const float* sptr = scale + (size_t)(bn * BN + srow) * (KDIM / 256);
  const int arx = srow & 7;

  f32x4 acc[4][4];
#pragma unroll
  for (int i = 0; i < 4; ++i)
#pragma unroll
    for (int j = 0; j < 4; ++j)
      acc[i][j] = (f32x4){0.f, 0.f, 0.f, 0.f};

  float bias_v[4];
#pragma unroll
  for (int n = 0; n < 4; ++n)
    bias_v[n] = bias[bn * BN + wc * 64 + n * 16 + (lane & 15)];

  for (int kt = 0; kt < KDIM / BK; ++kt) {
    const int k0 = kt * BK;

    // ---- global loads (in flight across the barrier) ----
    float4v av[8];
    int4v   bv[8];
#pragma unroll
    for (int j = 0; j < 8; ++j) av[j] = *(const float4v*)(aptr + k0 + 4 * j);
#pragma unroll
    for (int j = 0; j < 8; ++j) bv[j] = *(const int4v*)(bptr + k0 + 4 * j);
    const float inv = 1.0f / sptr[k0 >> 8];   // one quant group per BK step

    __syncthreads();   // previous iteration's reads complete

    // ---- convert + swizzled LDS write (4 x 16B chunks each of A, B) ----
#pragma unroll
    for (int c = 0; c < 4; ++c) {
      short8 pa, pb;
#pragma unroll
      for (int e = 0; e < 8; ++e) {
        const int v = c * 8 + e;
        pa[e] = (short)f2bf(av[v >> 2][v & 3]);
        pb[e] = (short)f2bf((float)bv[v >> 2][v & 3] * inv);
      }
      const int cc = shalf * 4 + c;
      *(short8*)(ldsA + srow * 128 + ((cc ^ arx) << 4)) = pa;
      *(short8*)(ldsB + srow * 128 + ((cc ^ arx) << 4)) = pb;
    }

    __syncthreads();   // tile visible to all waves

    // ---- LDS -> fragments (ds_read_b128, swizzle-matched) ----
    short8 af[4][2], bfr[4][2];
#pragma unroll
    for (int m = 0; m < 4; ++m) {
      const int r = wr * 64 + m * 16 + (lane & 15);
      const int rx = r & 7;
#pragma unroll
      for (int ks = 0; ks < 2; ++ks) {
        const int ch = ks * 4 + (lane >> 4);
        af[m][ks] = *(const short8*)(ldsA + r * 128 + ((ch ^ rx) << 4));
      }
    }
#pragma unroll
    for (int n = 0; n < 4; ++n) {
      const int r = wc * 64 + n * 16 + (lane & 15);
      const int rx = r & 7;
#pragma unroll
      for (int ks = 0; ks < 2; ++ks) {
        const int ch = ks * 4 + (lane >> 4);
        bfr[n][ks] = *(const short8*)(ldsB + r * 128 + ((ch ^ rx) << 4));
      }
    }

    // ---- MFMA: 32 per K-step, accumulate in fp32 ----
#pragma unroll
    for (int ks = 0; ks < 2; ++ks)
#pragma unroll
      for (int m = 0; m < 4; ++m)
#pragma unroll
        for (int n = 0; n < 4; ++n)
          acc[m][n] = __builtin_amdgcn_mfma_f32_16x16x32_bf16(
              af[m][ks], bfr[n][ks], acc[m][n], 0, 0, 0);
  }

  // ---- epilogue: bias + fp32 store (C/D map: col=lane&15, row=(lane>>4)*4+j) ----
#pragma unroll
  for (int m = 0; m < 4; ++m) {
    const int row0 = bm * BM + wr * 64 + m * 16 + (lane >> 4) * 4;
#pragma unroll
    for (int n = 0; n < 4; ++n) {
      const int col = bn * BN + wc * 64 + n * 16 + (lane & 15);
      const float bv_ = bias_v[n];
#pragma unroll
      for (int j = 0; j < 4; ++j)
        out[(size_t)(row0 + j) * NDIM + col] = acc[m][n][j] + bv_;
    }
  }
}

extern "C" void kernel_launch(void* const* d_in, const int* in_sizes, int n_in,
                              void* d_out, int out_size, void* d_ws, size_t ws_size,
                              hipStream_t stream) {
  const float* x     = (const float*)d_in[0];
  const int*   qw    = (const int*)d_in[1];
  const float* scale = (const float*)d_in[2];
  const float* bias  = (const float*)d_in[3];
  float* out = (float*)d_out;

  dim3 grid(NBM * NBN);
  dim3 block(256);
  hipLaunchKernelGGL(clinear_mfma, grid, block, 0, stream, x, qw, scale, bias, out);
}

// Round 2
// 1043.367 us; speedup vs baseline: 4.0212x; 4.0212x over previous
//
#include <hip/hip_runtime.h>
#include <hip/hip_bf16.h>
#include <stdint.h>

typedef __attribute__((ext_vector_type(8))) short short8;
typedef __attribute__((ext_vector_type(4))) float f32x4;
typedef __attribute__((ext_vector_type(4))) float float4v;
typedef __attribute__((ext_vector_type(4))) int int4v;

#define MDIM 8192
#define NDIM 11008
#define KDIM 4096
#define BM 128
#define BN 128
#define BK 64
#define NBM (MDIM / BM)   /* 64 */
#define NBN (NDIM / BN)   /* 86 */

// round-to-nearest-even f32 -> bf16
static __device__ __forceinline__ unsigned short f2bf(float f) {
  union { float f; unsigned int u; } v;
  v.f = f;
  unsigned int r = v.u + 0x7FFFu + ((v.u >> 16) & 1u);
  return (unsigned short)(r >> 16);
}

#define GLDS16(g, l) __builtin_amdgcn_global_load_lds(                         \
    (const __attribute__((address_space(1))) void*)(g),                        \
    (__attribute__((address_space(3))) void*)(l), 16, 0, 0)

// ---------------- pass 1a: x fp32 -> bf16 ----------------
__global__ __launch_bounds__(256) void conv_x(const float* __restrict__ x,
                                              unsigned short* __restrict__ xb) {
  const size_t i = ((size_t)blockIdx.x * 256 + threadIdx.x) * 8;
  float4v v0 = *(const float4v*)(x + i);
  float4v v1 = *(const float4v*)(x + i + 4);
  short8 o;
#pragma unroll
  for (int e = 0; e < 4; ++e) { o[e] = (short)f2bf(v0[e]); o[4 + e] = (short)f2bf(v1[e]); }
  *(short8*)(xb + i) = o;
}

// ---------------- pass 1b: qweight int + scale -> bf16 ----------------
__global__ __launch_bounds__(256) void conv_w(const int* __restrict__ qw,
                                              const float* __restrict__ scale,
                                              unsigned short* __restrict__ wb) {
  const size_t i = ((size_t)blockIdx.x * 256 + threadIdx.x) * 8;
  int4v q0 = *(const int4v*)(qw + i);
  int4v q1 = *(const int4v*)(qw + i + 4);
  const float inv = 1.0f / scale[i >> 8];   // group size 256, 8 | 256
  short8 o;
#pragma unroll
  for (int e = 0; e < 4; ++e) {
    o[e]     = (short)f2bf((float)q0[e] * inv);
    o[4 + e] = (short)f2bf((float)q1[e] * inv);
  }
  *(short8*)(wb + i) = o;
}

// ---------------- pass 2: bf16 GEMM, m97 structure ----------------
__global__ __launch_bounds__(256, 3) void gemm_bf16(
    const unsigned short* __restrict__ xa,
    const unsigned short* __restrict__ wb,
    const float* __restrict__ bias,
    float* __restrict__ out)
{
  __shared__ unsigned short ldsA[BM * BK];   // 16 KB, linear (global_load_lds dest)
  __shared__ unsigned short ldsB[BN * BK];   // 16 KB

  const int t = threadIdx.x;
  const int lane = t & 63;
  const int wave = t >> 6;
  const int wr = wave >> 1;
  const int wc = wave & 1;

  const int bm = blockIdx.x / NBN;
  const int bn = blockIdx.x % NBN;

  // staging: wave handles 4 chunks of 1KB (= 8 rows x 64 cols bf16) per tile
  const int g0 = wave * 4;                       // first chunk id (0..15)
  const int srow = (lane >> 3);                  // row within chunk (0..7)
  const int scol = (lane & 7) * 8;               // col (bf16 elems)
  const unsigned short* aSrc = xa + (size_t)(bm * BM) * KDIM + scol;
  const unsigned short* bSrc = wb + (size_t)(bn * BN) * KDIM + scol;

  f32x4 acc[4][4];
#pragma unroll
  for (int i = 0; i < 4; ++i)
#pragma unroll
    for (int j = 0; j < 4; ++j)
      acc[i][j] = (f32x4){0.f, 0.f, 0.f, 0.f};

  float bias_v[4];
#pragma unroll
  for (int n = 0; n < 4; ++n)
    bias_v[n] = bias[bn * BN + wc * 64 + n * 16 + (lane & 15)];

  for (int kt = 0; kt < KDIM / BK; ++kt) {
    const int k0 = kt * BK;

    __syncthreads();   // all waves done reading LDS from previous step
#pragma unroll
    for (int c = 0; c < 4; ++c) {
      const int rowc = (g0 + c) * 8 + srow;
      GLDS16(aSrc + (size_t)rowc * KDIM + k0, &ldsA[(g0 + c) * 512]);
      GLDS16(bSrc + (size_t)rowc * KDIM + k0, &ldsB[(g0 + c) * 512]);
    }
    __syncthreads();   // vmcnt(0) drain + tile visible

#pragma unroll
    for (int ks = 0; ks < 2; ++ks) {
      short8 af[4], bfr[4];
#pragma unroll
      for (int m = 0; m < 4; ++m)
        af[m] = *(const short8*)&ldsA[(wr * 64 + m * 16 + (lane & 15)) * BK +
                                      ks * 32 + (lane >> 4) * 8];
#pragma unroll
      for (int n = 0; n < 4; ++n)
        bfr[n] = *(const short8*)&ldsB[(wc * 64 + n * 16 + (lane & 15)) * BK +
                                       ks * 32 + (lane >> 4) * 8];
#pragma unroll
      for (int m = 0; m < 4; ++m)
#pragma unroll
        for (int n = 0; n < 4; ++n)
          acc[m][n] = __builtin_amdgcn_mfma_f32_16x16x32_bf16(
              af[m], bfr[n], acc[m][n], 0, 0, 0);
    }
  }

  // epilogue: bias + fp32 store (C/D map: col=lane&15, row=(lane>>4)*4+j)
#pragma unroll
  for (int m = 0; m < 4; ++m) {
    const int row0 = bm * BM + wr * 64 + m * 16 + (lane >> 4) * 4;
#pragma unroll
    for (int n = 0; n < 4; ++n) {
      const int col = bn * BN + wc * 64 + n * 16 + (lane & 15);
      const float bv_ = bias_v[n];
#pragma unroll
      for (int j = 0; j < 4; ++j)
        out[(size_t)(row0 + j) * NDIM + col] = acc[m][n][j] + bv_;
    }
  }
}

// ---------------- fallback: fused single-pass (round-1 kernel) ----------------
__global__ __launch_bounds__(256, 2) void clinear_fused(
    const float* __restrict__ x,
    const int* __restrict__ qw,
    const float* __restrict__ scale,
    const float* __restrict__ bias,
    float* __restrict__ out)
{
  __shared__ unsigned char ldsA[BM * BK * 2];
  __shared__ unsigned char ldsB[BN * BK * 2];

  const int t = threadIdx.x;
  const int lane = t & 63;
  const int wave = t >> 6;
  const int wr = wave >> 1;
  const int wc = wave & 1;

  const int bid = blockIdx.x;
  const int cpx = (NBM * NBN) >> 3;
  const int swz = (bid & 7) * cpx + (bid >> 3);
  const int bm = swz / NBN;
  const int bn = swz % NBN;

  const int srow = t >> 1;
  const int shalf = t & 1;
  const float* aptr = x  + (size_t)(bm * BM + srow) * KDIM + shalf * 32;
  const int*   bptr = qw + (size_t)(bn * BN + srow) * KDIM + shalf * 32;
  const float* sptr = scale + (size_t)(bn * BN + srow) * (KDIM / 256);
  const int arx = srow & 7;

  f32x4 acc[4][4];
#pragma unroll
  for (int i = 0; i < 4; ++i)
#pragma unroll
    for (int j = 0; j < 4; ++j)
      acc[i][j] = (f32x4){0.f, 0.f, 0.f, 0.f};

  float bias_v[4];
#pragma unroll
  for (int n = 0; n < 4; ++n)
    bias_v[n] = bias[bn * BN + wc * 64 + n * 16 + (lane & 15)];

  for (int kt = 0; kt < KDIM / BK; ++kt) {
    const int k0 = kt * BK;
    float4v av[8];
    int4v   bv[8];
#pragma unroll
    for (int j = 0; j < 8; ++j) av[j] = *(const float4v*)(aptr + k0 + 4 * j);
#pragma unroll
    for (int j = 0; j < 8; ++j) bv[j] = *(const int4v*)(bptr + k0 + 4 * j);
    const float inv = 1.0f / sptr[k0 >> 8];

    __syncthreads();
#pragma unroll
    for (int c = 0; c < 4; ++c) {
      short8 pa, pb;
#pragma unroll
      for (int e = 0; e < 8; ++e) {
        const int v = c * 8 + e;
        pa[e] = (short)f2bf(av[v >> 2][v & 3]);
        pb[e] = (short)f2bf((float)bv[v >> 2][v & 3] * inv);
      }
      const int cc = shalf * 4 + c;
      *(short8*)(ldsA + srow * 128 + ((cc ^ arx) << 4)) = pa;
      *(short8*)(ldsB + srow * 128 + ((cc ^ arx) << 4)) = pb;
    }
    __syncthreads();

    short8 af[4][2], bfr[4][2];
#pragma unroll
    for (int m = 0; m < 4; ++m) {
      const int r = wr * 64 + m * 16 + (lane & 15);
      const int rx = r & 7;
#pragma unroll
      for (int ks = 0; ks < 2; ++ks) {
        const int ch = ks * 4 + (lane >> 4);
        af[m][ks] = *(const short8*)(ldsA + r * 128 + ((ch ^ rx) << 4));
      }
    }
#pragma unroll
    for (int n = 0; n < 4; ++n) {
      const int r = wc * 64 + n * 16 + (lane & 15);
      const int rx = r & 7;
#pragma unroll
      for (int ks = 0; ks < 2; ++ks) {
        const int ch = ks * 4 + (lane >> 4);
        bfr[n][ks] = *(const short8*)(ldsB + r * 128 + ((ch ^ rx) << 4));
      }
    }
#pragma unroll
    for (int ks = 0; ks < 2; ++ks)
#pragma unroll
      for (int m = 0; m < 4; ++m)
#pragma unroll
        for (int n = 0; n < 4; ++n)
          acc[m][n] = __builtin_amdgcn_mfma_f32_16x16x32_bf16(
              af[m][ks], bfr[n][ks], acc[m][n], 0, 0, 0);
  }

#pragma unroll
  for (int m = 0; m < 4; ++m) {
    const int row0 = bm * BM + wr * 64 + m * 16 + (lane >> 4) * 4;
#pragma unroll
    for (int n = 0; n < 4; ++n) {
      const int col = bn * BN + wc * 64 + n * 16 + (lane & 15);
      const float bv_ = bias_v[n];
#pragma unroll
      for (int j = 0; j < 4; ++j)
        out[(size_t)(row0 + j) * NDIM + col] = acc[m][n][j] + bv_;
    }
  }
}

extern "C" void kernel_launch(void* const* d_in, const int* in_sizes, int n_in,
                              void* d_out, int out_size, void* d_ws, size_t ws_size,
                              hipStream_t stream) {
  const float* x     = (const float*)d_in[0];
  const int*   qw    = (const int*)d_in[1];
  const float* scale = (const float*)d_in[2];
  const float* bias  = (const float*)d_in[3];
  float* out = (float*)d_out;

  const size_t needX = (size_t)MDIM * KDIM * sizeof(unsigned short);  // 64 MiB
  const size_t needW = (size_t)NDIM * KDIM * sizeof(unsigned short);  // 86 MiB

  if (ws_size >= needX + needW) {
    unsigned short* xb = (unsigned short*)d_ws;
    unsigned short* wbuf = (unsigned short*)((char*)d_ws + needX);
    hipLaunchKernelGGL(conv_x, dim3((MDIM * (size_t)KDIM) / (8 * 256)), dim3(256),
                       0, stream, x, xb);
    hipLaunchKernelGGL(conv_w, dim3((NDIM * (size_t)KDIM) / (8 * 256)), dim3(256),
                       0, stream, qw, scale, wbuf);
    hipLaunchKernelGGL(gemm_bf16, dim3(NBM * NBN), dim3(256), 0, stream,
                       xb, wbuf, bias, out);
  } else {
    hipLaunchKernelGGL(clinear_fused, dim3(NBM * NBN), dim3(256), 0, stream,
                       x, qw, scale, bias, out);
  }
}

// Round 4
// 741.007 us; speedup vs baseline: 5.6620x; 1.4080x over previous
//
#include <hip/hip_runtime.h>
#include <hip/hip_bf16.h>
#include <stdint.h>

typedef __attribute__((ext_vector_type(8))) short short8;
typedef __attribute__((ext_vector_type(4))) float f32x4;
typedef __attribute__((ext_vector_type(4))) float float4v;
typedef __attribute__((ext_vector_type(4))) int int4v;

#define MDIM 8192
#define NDIM 11008
#define KDIM 4096
#define NT   (KDIM / 64)      /* 64 K-tiles */
#define NBM2 (MDIM / 256)     /* 32 */
#define NBN2 (NDIM / 256)     /* 43 */

static __device__ __forceinline__ unsigned short f2bf(float f) {
  union { float f; unsigned int u; } v;
  v.f = f;
  unsigned int r = v.u + 0x7FFFu + ((v.u >> 16) & 1u);
  return (unsigned short)(r >> 16);
}

#define GLDS16(g, l) __builtin_amdgcn_global_load_lds(                         \
    (const __attribute__((address_space(1))) void*)(g),                        \
    (__attribute__((address_space(3))) void*)(l), 16, 0, 0)

// ---------------- pass 1a: x fp32 -> bf16 ----------------
__global__ __launch_bounds__(256) void conv_x(const float* __restrict__ x,
                                              unsigned short* __restrict__ xb) {
  const size_t i = ((size_t)blockIdx.x * 256 + threadIdx.x) * 8;
  float4v v0 = *(const float4v*)(x + i);
  float4v v1 = *(const float4v*)(x + i + 4);
  short8 o;
#pragma unroll
  for (int e = 0; e < 4; ++e) { o[e] = (short)f2bf(v0[e]); o[4 + e] = (short)f2bf(v1[e]); }
  *(short8*)(xb + i) = o;
}

// ---------------- pass 1b: qweight int + scale -> bf16 ----------------
__global__ __launch_bounds__(256) void conv_w(const int* __restrict__ qw,
                                              const float* __restrict__ scale,
                                              unsigned short* __restrict__ wb) {
  const size_t i = ((size_t)blockIdx.x * 256 + threadIdx.x) * 8;
  int4v q0 = *(const int4v*)(qw + i);
  int4v q1 = *(const int4v*)(qw + i + 4);
  const float inv = 1.0f / scale[i >> 8];
  short8 o;
#pragma unroll
  for (int e = 0; e < 4; ++e) {
    o[e]     = (short)f2bf((float)q0[e] * inv);
    o[4 + e] = (short)f2bf((float)q1[e] * inv);
  }
  *(short8*)(wb + i) = o;
}

// ---------------- pass 2: 256x256 multi-phase bf16 GEMM ----------------
__global__ __launch_bounds__(512, 2) void gemm256(
    const unsigned short* __restrict__ xa,
    const unsigned short* __restrict__ wb,
    const float* __restrict__ bias,
    float* __restrict__ out)
{
  __shared__ unsigned char lds[131072];
  unsigned char* ldsA = lds;            // [2][32768]: 256 rows x 64 bf16, swizzled slots
  unsigned char* ldsB = lds + 65536;    // [2][32768]

  const int t = threadIdx.x;
  const int lane = t & 63;
  const int w = t >> 6;        // wave 0..7
  const int wr = w >> 2;       // 0..1  (A half)
  const int wc = w & 3;        // 0..3  (B quarter)
  const int lh = lane >> 4;    // 0..3
  const int l15 = lane & 15;
  const int l7 = lane & 7;
  const int lr = lane >> 3;    // 0..7 staging row within 8-row strip

  // XCD-bijective swizzle: 1376 = 8 * 172
  const int bid = blockIdx.x;
  const int swz = (bid & 7) * (NBM2 * NBN2 / 8) + (bid >> 3);
  const int bm = swz / NBN2;
  const int bn = swz % NBN2;

  // per-lane LDS read base: row-part l15*128, slot ((ks*4+lh)^l7)<<4; ks=1 flips bit 6
  const int rdBase0 = l15 * 128 + ((lh ^ l7) << 4);

  // staging: linear LDS dest (base+lane*16) <- pre-swizzled global source
  // phys (row=lr, slot=l7) holds logical col8 = l7 ^ lr  (strip bases are multiples of 8)
  const size_t srcOff = (size_t)lr * KDIM + ((l7 ^ lr) << 3);

  const unsigned short* aS = xa + ((size_t)(bm * 256 + wr * 128 + wc * 8)) * KDIM + srcOff;
  const unsigned short* bS = wb + ((size_t)(bn * 256 + w * 32)) * KDIM + srcOff;
  const int aDst = (wr * 128 + wc * 8) * 128;   // + q*4096 + cur*32768
  const int bDst = (w * 32) * 128;              // + c*1024 + cur*32768

  float bias_v[4];
#pragma unroll
  for (int n = 0; n < 4; ++n) bias_v[n] = bias[bn * 256 + wc * 64 + n * 16 + l15];

  f32x4 acc[8][4];
#pragma unroll
  for (int m = 0; m < 8; ++m)
#pragma unroll
    for (int n = 0; n < 4; ++n) acc[m][n] = (f32x4){0.f, 0.f, 0.f, 0.f};

#define STAGE_B4(cur, kt) {                                                    \
  _Pragma("unroll")                                                            \
  for (int c = 0; c < 4; ++c)                                                  \
    GLDS16(bS + (size_t)(c * 8) * KDIM + (kt) * 64,                            \
           ldsB + (cur) * 32768 + bDst + c * 1024); }
#define STAGE_A1(cur, kt, q)                                                   \
    GLDS16(aS + (size_t)((q) * 32) * KDIM + (kt) * 64,                         \
           ldsA + (cur) * 32768 + aDst + (q) * 4096);

#define RD_A(cur, m, ks) (*(const short8*)(ldsA + (cur) * 32768 + wr * 16384 + \
                          (m) * 2048 + (rdBase0 ^ ((ks) * 64))))
#define RD_B(cur, n, ks) (*(const short8*)(ldsB + (cur) * 32768 + wc * 8192 +  \
                          (n) * 2048 + (rdBase0 ^ ((ks) * 64))))

// Per-wave load queue per tile (issue order): B1 B2 B3 B4 A0 | A1 | A2 | A3.
// Steady-state waits (7,7,7,3): phase boundary drains exactly the strip the
// next phase reads. Last tile issues nothing -> exact drains (2,1,0,0).
#define PHASE(cur, kt, q, WAITN) {                                             \
  short8 a00 = RD_A(cur, 2 * (q),     0);                                      \
  short8 a01 = RD_A(cur, 2 * (q),     1);                                      \
  short8 a10 = RD_A(cur, 2 * (q) + 1, 0);                                      \
  short8 a11 = RD_A(cur, 2 * (q) + 1, 1);                                      \
  if ((q) == 0) {                                                              \
    _Pragma("unroll")                                                          \
    for (int n = 0; n < 4; ++n) {                                              \
      bf[n][0] = RD_B(cur, n, 0);                                              \
      bf[n][1] = RD_B(cur, n, 1);                                              \
    }                                                                          \
  }                                                                            \
  if ((kt) + 1 < NT) {                                                         \
    if ((q) == 0) { STAGE_B4((cur) ^ 1, (kt) + 1); STAGE_A1((cur) ^ 1, (kt) + 1, 0); } \
    else          { STAGE_A1((cur) ^ 1, (kt) + 1, q); }                        \
  }                                                                            \
  __builtin_amdgcn_s_barrier();                                                \
  __builtin_amdgcn_s_setprio(1);                                               \
  _Pragma("unroll")                                                            \
  for (int n = 0; n < 4; ++n) {                                                \
    acc[2*(q)][n]   = __builtin_amdgcn_mfma_f32_16x16x32_bf16(a00, bf[n][0], acc[2*(q)][n], 0, 0, 0);     \
    acc[2*(q)][n]   = __builtin_amdgcn_mfma_f32_16x16x32_bf16(a01, bf[n][1], acc[2*(q)][n], 0, 0, 0);     \
    acc[2*(q)+1][n] = __builtin_amdgcn_mfma_f32_16x16x32_bf16(a10, bf[n][0], acc[2*(q)+1][n], 0, 0, 0);   \
    acc[2*(q)+1][n] = __builtin_amdgcn_mfma_f32_16x16x32_bf16(a11, bf[n][1], acc[2*(q)+1][n], 0, 0, 0);   \
  }                                                                            \
  __builtin_amdgcn_s_setprio(0);                                               \
  asm volatile("s_waitcnt vmcnt(" WAITN ")" ::: "memory");                     \
  __builtin_amdgcn_s_barrier(); }

#define TILE(cur, kt, W0, W1, W2, W3) { short8 bf[4][2];                       \
  PHASE(cur, kt, 0, W0)                                                        \
  PHASE(cur, kt, 1, W1)                                                        \
  PHASE(cur, kt, 2, W2)                                                        \
  PHASE(cur, kt, 3, W3) }

  // prologue: tile 0's strips in steady-state order [B x4, A q0..q3]
  STAGE_B4(0, 0);
  STAGE_A1(0, 0, 0);
  STAGE_A1(0, 0, 1);
  STAGE_A1(0, 0, 2);
  STAGE_A1(0, 0, 3);
  asm volatile("s_waitcnt vmcnt(3)" ::: "memory");
  __builtin_amdgcn_s_barrier();

  for (int kt = 0; kt < NT - 2; kt += 2) {
    TILE(0, kt,     "7", "7", "7", "3")
    TILE(1, kt + 1, "7", "7", "7", "3")
  }
  TILE(0, NT - 2, "7", "7", "7", "3")
  TILE(1, NT - 1, "2", "1", "0", "0")   // last tile: exact drains (no staging issued)

  // epilogue: bias + fp32 store (C/D map: col=lane&15, row=(lane>>4)*4+j)
#pragma unroll
  for (int m = 0; m < 8; ++m) {
    const int row0 = bm * 256 + wr * 128 + m * 16 + lh * 4;
#pragma unroll
    for (int n = 0; n < 4; ++n) {
      const int col = bn * 256 + wc * 64 + n * 16 + l15;
      const float bv_ = bias_v[n];
#pragma unroll
      for (int j = 0; j < 4; ++j)
        out[(size_t)(row0 + j) * NDIM + col] = acc[m][n][j] + bv_;
    }
  }
#undef TILE
#undef PHASE
#undef RD_A
#undef RD_B
#undef STAGE_A1
#undef STAGE_B4
}

// ---------------- fallback: fused single-pass (round-1 kernel) ----------------
__global__ __launch_bounds__(256, 2) void clinear_fused(
    const float* __restrict__ x,
    const int* __restrict__ qw,
    const float* __restrict__ scale,
    const float* __restrict__ bias,
    float* __restrict__ out)
{
  __shared__ unsigned char ldsA[128 * 64 * 2];
  __shared__ unsigned char ldsB[128 * 64 * 2];

  const int t = threadIdx.x;
  const int lane = t & 63;
  const int wave = t >> 6;
  const int wr = wave >> 1;
  const int wc = wave & 1;

  const int NBN = NDIM / 128;
  const int bid = blockIdx.x;
  const int cpx = ((MDIM / 128) * NBN) >> 3;
  const int swz = (bid & 7) * cpx + (bid >> 3);
  const int bm = swz / NBN;
  const int bn = swz % NBN;

  const int srow = t >> 1;
  const int shalf = t & 1;
  const float* aptr = x  + (size_t)(bm * 128 + srow) * KDIM + shalf * 32;
  const int*   bptr = qw + (size_t)(bn * 128 + srow) * KDIM + shalf * 32;
  const float* sptr = scale + (size_t)(bn * 128 + srow) * (KDIM / 256);
  const int arx = srow & 7;

  f32x4 acc[4][4];
#pragma unroll
  for (int i = 0; i < 4; ++i)
#pragma unroll
    for (int j = 0; j < 4; ++j)
      acc[i][j] = (f32x4){0.f, 0.f, 0.f, 0.f};

  float bias_v[4];
#pragma unroll
  for (int n = 0; n < 4; ++n)
    bias_v[n] = bias[bn * 128 + wc * 64 + n * 16 + (lane & 15)];

  for (int kt = 0; kt < KDIM / 64; ++kt) {
    const int k0 = kt * 64;
    float4v av[8];
    int4v   bv[8];
#pragma unroll
    for (int j = 0; j < 8; ++j) av[j] = *(const float4v*)(aptr + k0 + 4 * j);
#pragma unroll
    for (int j = 0; j < 8; ++j) bv[j] = *(const int4v*)(bptr + k0 + 4 * j);
    const float inv = 1.0f / sptr[k0 >> 8];

    __syncthreads();
#pragma unroll
    for (int c = 0; c < 4; ++c) {
      short8 pa, pb;
#pragma unroll
      for (int e = 0; e < 8; ++e) {
        const int v = c * 8 + e;
        pa[e] = (short)f2bf(av[v >> 2][v & 3]);
        pb[e] = (short)f2bf((float)bv[v >> 2][v & 3] * inv);
      }
      const int cc = shalf * 4 + c;
      *(short8*)(ldsA + srow * 128 + ((cc ^ arx) << 4)) = pa;
      *(short8*)(ldsB + srow * 128 + ((cc ^ arx) << 4)) = pb;
    }
    __syncthreads();

    short8 af[4][2], bfr[4][2];
#pragma unroll
    for (int m = 0; m < 4; ++m) {
      const int r = wr * 64 + m * 16 + (lane & 15);
      const int rx = r & 7;
#pragma unroll
      for (int ks = 0; ks < 2; ++ks) {
        const int ch = ks * 4 + (lane >> 4);
        af[m][ks] = *(const short8*)(ldsA + r * 128 + ((ch ^ rx) << 4));
      }
    }
#pragma unroll
    for (int n = 0; n < 4; ++n) {
      const int r = wc * 64 + n * 16 + (lane & 15);
      const int rx = r & 7;
#pragma unroll
      for (int ks = 0; ks < 2; ++ks) {
        const int ch = ks * 4 + (lane >> 4);
        bfr[n][ks] = *(const short8*)(ldsB + r * 128 + ((ch ^ rx) << 4));
      }
    }
#pragma unroll
    for (int ks = 0; ks < 2; ++ks)
#pragma unroll
      for (int m = 0; m < 4; ++m)
#pragma unroll
        for (int n = 0; n < 4; ++n)
          acc[m][n] = __builtin_amdgcn_mfma_f32_16x16x32_bf16(
              af[m][ks], bfr[n][ks], acc[m][n], 0, 0, 0);
  }

#pragma unroll
  for (int m = 0; m < 4; ++m) {
    const int row0 = bm * 128 + wr * 64 + m * 16 + (lane >> 4) * 4;
#pragma unroll
    for (int n = 0; n < 4; ++n) {
      const int col = bn * 128 + wc * 64 + n * 16 + (lane & 15);
      const float bv_ = bias_v[n];
#pragma unroll
      for (int j = 0; j < 4; ++j)
        out[(size_t)(row0 + j) * NDIM + col] = acc[m][n][j] + bv_;
    }
  }
}

extern "C" void kernel_launch(void* const* d_in, const int* in_sizes, int n_in,
                              void* d_out, int out_size, void* d_ws, size_t ws_size,
                              hipStream_t stream) {
  const float* x     = (const float*)d_in[0];
  const int*   qw    = (const int*)d_in[1];
  const float* scale = (const float*)d_in[2];
  const float* bias  = (const float*)d_in[3];
  float* out = (float*)d_out;

  const size_t needX = (size_t)MDIM * KDIM * sizeof(unsigned short);
  const size_t needW = (size_t)NDIM * KDIM * sizeof(unsigned short);

  if (ws_size >= needX + needW) {
    unsigned short* xb   = (unsigned short*)d_ws;
    unsigned short* wbuf = (unsigned short*)((char*)d_ws + needX);
    hipLaunchKernelGGL(conv_x, dim3((MDIM * (size_t)KDIM) / (8 * 256)), dim3(256),
                       0, stream, x, xb);
    hipLaunchKernelGGL(conv_w, dim3((NDIM * (size_t)KDIM) / (8 * 256)), dim3(256),
                       0, stream, qw, scale, wbuf);
    hipLaunchKernelGGL(gemm256, dim3(NBM2 * NBN2), dim3(512), 0, stream,
                       xb, wbuf, bias, out);
  } else {
    hipLaunchKernelGGL(clinear_fused, dim3((MDIM / 128) * (NDIM / 128)), dim3(256),
                       0, stream, x, qw, scale, bias, out);
  }
}